// Round 1
// baseline (19705.331 us; speedup 1.0000x reference)
//
#include <hip/hip_runtime.h>

#define V 32000
#define D 256
#define H 256
#define T 128
#define B 32
#define SOS 126
#define H2 512

__device__ __forceinline__ float sigf(float x) { return 1.f / (1.f + __expf(-x)); }
__device__ __forceinline__ float ftanh(float x) {
    x = fminf(15.f, fmaxf(-15.f, x));
    float e = __expf(2.f * x);
    return (e - 1.f) / (e + 1.f);
}

// ---------------- encoder embedding gather: E[b*T+t][k] = emb_enc[x[b*T+t]][k]
__global__ __launch_bounds__(256) void k_embed(const int* __restrict__ x,
                                               const float* __restrict__ emb,
                                               float* __restrict__ E) {
    int idx = blockIdx.x * 256 + threadIdx.x;   // B*T*D = 1048576 exactly
    int bt = idx >> 8;
    int k  = idx & 255;
    E[idx] = emb[x[bt] * D + k];
}

// ---------------- one encoder timestep, both directions.
// grid 256 = dir(2) x ublk(128, 2 units each); block 256
__global__ __launch_bounds__(256) void k_enc_step(
    const float* __restrict__ E, const float* __restrict__ h_cur, float* __restrict__ h_nxt,
    float* __restrict__ c_st, float* __restrict__ enc_out,
    const float* __restrict__ Wih_f, const float* __restrict__ Whh_f,
    const float* __restrict__ bih_f, const float* __restrict__ bhh_f,
    const float* __restrict__ Wih_b, const float* __restrict__ Whh_b,
    const float* __restrict__ bih_b, const float* __restrict__ bhh_b, int t) {
    int tid = threadIdx.x;
    int dir = blockIdx.x >> 7;
    int u0 = (blockIdx.x & 127) * 2;
    int b = tid & 31, q = tid >> 5;
    int g = q & 3, ul = q >> 2;
    int u = u0 + ul;
    int grow = g * H + u;
    const float* Wih = dir ? Wih_b : Wih_f;
    const float* Whh = dir ? Whh_b : Whh_f;
    const float* bih = dir ? bih_b : bih_f;
    const float* bhh = dir ? bhh_b : bhh_f;

    float a0 = 0, a1 = 0, a2 = 0, a3 = 0;
    const float* e = E + (b * T + t) * D;
    const float* wr = Wih + grow * D;
    for (int k = 0; k < D; k += 4) {
        float4 w = *(const float4*)(wr + k);
        float4 xv = *(const float4*)(e + k);
        a0 = fmaf(w.x, xv.x, a0); a1 = fmaf(w.y, xv.y, a1);
        a2 = fmaf(w.z, xv.z, a2); a3 = fmaf(w.w, xv.w, a3);
    }
    const float* hp = h_cur + dir * (B * H) + b * H;
    const float* wr2 = Whh + grow * H;
    for (int k = 0; k < H; k += 4) {
        float4 w = *(const float4*)(wr2 + k);
        float4 xv = *(const float4*)(hp + k);
        a0 = fmaf(w.x, xv.x, a0); a1 = fmaf(w.y, xv.y, a1);
        a2 = fmaf(w.z, xv.z, a2); a3 = fmaf(w.w, xv.w, a3);
    }
    float z = (a0 + a1) + (a2 + a3) + bih[grow] + bhh[grow];
    __shared__ float zs[8][32];
    zs[q][b] = z;
    __syncthreads();
    if (tid < 64) {
        int b2 = tid & 31, ul2 = tid >> 5;
        int uu = u0 + ul2;
        float zi = zs[ul2 * 4 + 0][b2], zf = zs[ul2 * 4 + 1][b2];
        float zg = zs[ul2 * 4 + 2][b2], zo = zs[ul2 * 4 + 3][b2];
        int ci = dir * (B * H) + b2 * H + uu;
        float c2 = sigf(zf) * c_st[ci] + sigf(zi) * ftanh(zg);
        float h2 = sigf(zo) * ftanh(c2);
        c_st[ci] = c2;
        h_nxt[dir * (B * H) + b2 * H + uu] = h2;
        enc_out[(b2 * T + t) * H2 + dir * H + uu] = h2;
    }
}

// ---------------- proj_e = enc_out @ Wa_e^T   (4096 x 512) @ (512 x 512)^T
// grid 256: 16 (b,t)-rows per block
__global__ __launch_bounds__(256) void k_proj(const float* __restrict__ enc_out,
                                              const float* __restrict__ Wa_e,
                                              float* __restrict__ proj_e) {
    __shared__ float X[16][512];
    int tid = threadIdx.x;
    int r0 = blockIdx.x * 16;
    for (int i = tid; i < 16 * 512; i += 256) {
        int r = i >> 9, k = i & 511;
        X[r][k] = enc_out[(r0 + r) * H2 + k];
    }
    __syncthreads();
    int j0 = tid * 2;
    float acc0[16], acc1[16];
#pragma unroll
    for (int r = 0; r < 16; ++r) { acc0[r] = 0.f; acc1[r] = 0.f; }
    const float* w0 = Wa_e + j0 * H2;
    const float* w1 = Wa_e + (j0 + 1) * H2;
    for (int k = 0; k < H2; k += 4) {
        float4 wa = *(const float4*)(w0 + k);
        float4 wb = *(const float4*)(w1 + k);
#pragma unroll
        for (int r = 0; r < 16; ++r) {
            float4 xv = *(const float4*)(&X[r][k]);
            acc0[r] = fmaf(wa.x, xv.x, acc0[r]); acc0[r] = fmaf(wa.y, xv.y, acc0[r]);
            acc0[r] = fmaf(wa.z, xv.z, acc0[r]); acc0[r] = fmaf(wa.w, xv.w, acc0[r]);
            acc1[r] = fmaf(wb.x, xv.x, acc1[r]); acc1[r] = fmaf(wb.y, xv.y, acc1[r]);
            acc1[r] = fmaf(wb.z, xv.z, acc1[r]); acc1[r] = fmaf(wb.w, xv.w, acc1[r]);
        }
    }
#pragma unroll
    for (int r = 0; r < 16; ++r) {
        float2 st; st.x = acc0[r]; st.y = acc1[r];
        *(float2*)(proj_e + (r0 + r) * H2 + j0) = st;
    }
}

// ---------------- decoder init: h0/c0 = concat of final enc states; h2T (k-major) copy
__global__ __launch_bounds__(256) void k_init_dec(const float* __restrict__ h_enc0,
                                                  const float* __restrict__ c_enc,
                                                  float* __restrict__ h_dec0,
                                                  float* __restrict__ c_dec,
                                                  float* __restrict__ h2T) {
    int idx = blockIdx.x * 256 + threadIdx.x;   // 16384
    int b = idx >> 9, u = idx & 511;
    int dir = u >> 8, uu = u & 255;
    float hv = h_enc0[dir * (B * H) + b * H + uu];
    float cv = c_enc[dir * (B * H) + b * H + uu];
    h_dec0[b * H2 + u] = hv;
    c_dec[b * H2 + u] = cv;
    h2T[u * B + b] = hv;
}

// ---------------- q0 = h0 @ Wa_h^T (one time; later steps piggyback on k_logits)
__global__ __launch_bounds__(256) void k_qinit(const float* __restrict__ h_dec0,
                                               const float* __restrict__ Wa_h,
                                               float* __restrict__ q_buf) {
    int idx = blockIdx.x * 256 + threadIdx.x;   // 16384
    int b = idx & 31, j = idx >> 5;
    const float* hr = h_dec0 + b * H2;
    const float* wr = Wa_h + j * H2;
    float a0 = 0, a1 = 0, a2 = 0, a3 = 0;
    for (int k = 0; k < H2; k += 4) {
        float4 w = *(const float4*)(wr + k);
        float4 xv = *(const float4*)(hr + k);
        a0 = fmaf(w.x, xv.x, a0); a1 = fmaf(w.y, xv.y, a1);
        a2 = fmaf(w.z, xv.z, a2); a3 = fmaf(w.w, xv.w, a3);
    }
    q_buf[b * H2 + j] = (a0 + a1) + (a2 + a3);
}

// ---------------- K1: finalize prev step (argmax -> tok, lse) + attention + xcat
// grid 32 (one per batch) x 512 threads. finalize=1: only phase 0 (for t=128 tail).
__global__ __launch_bounds__(512) void k_attn(
    const float* __restrict__ proj_e, const float* __restrict__ enc_out,
    const float* __restrict__ emb_dec, const float* __restrict__ q_buf,
    const float* __restrict__ b_a, const float* __restrict__ v_a,
    const float* __restrict__ Pm, const float* __restrict__ Ps, const int* __restrict__ Pi,
    float* __restrict__ lse, float* __restrict__ xcat, int t, int finalize) {
    __shared__ float rm[512]; __shared__ float rs[512]; __shared__ int ri[512];
    __shared__ float es[128]; __shared__ float wsm[128]; __shared__ float sred[128];
    __shared__ int tok_sh;
    int tid = threadIdx.x;
    int b = blockIdx.x;
    int tokb = SOS;

    if (t > 0) {
        float m = -INFINITY, s = 0.f; int mi = 0x7fffffff;
        if (tid < 500) { m = Pm[tid * 32 + b]; s = Ps[tid * 32 + b]; mi = Pi[tid * 32 + b]; }
        rm[tid] = m; rs[tid] = s; ri[tid] = mi;
        __syncthreads();
        for (int off = 256; off >= 1; off >>= 1) {
            if (tid < off) {
                float m1 = rm[tid], m2 = rm[tid + off];
                float s1 = rs[tid], s2 = rs[tid + off];
                int i1 = ri[tid], i2 = ri[tid + off];
                float m_, s_; int i_;
                if (m2 > m1)      { m_ = m2; s_ = s2 + s1 * __expf(m1 - m2); i_ = i2; }
                else if (m1 > m2) { m_ = m1; s_ = s1 + s2 * __expf(m2 - m1); i_ = i1; }
                else              { m_ = m1; s_ = s1 + s2; i_ = (i1 < i2) ? i1 : i2; }
                rm[tid] = m_; rs[tid] = s_; ri[tid] = i_;
            }
            __syncthreads();
        }
        if (tid == 0) {
            lse[b * T + (t - 1)] = rm[0] + logf(rs[0]);
            tok_sh = ri[0];
        }
        __syncthreads();
        tokb = tok_sh;
    }
    if (finalize) return;

    // phase 1: embedding -> xcat[0:256]
    if (tid < 256) xcat[b * 768 + tid] = emb_dec[tokb * D + tid];

    // phase 2: energy[t2] = sum_j tanh(proj_e + q + b_a) * v_a
    int l = tid & 63, w = tid >> 6;
    float q8[8], va8[8];
    {
        const float* qp = q_buf + b * H2 + l * 8;
        const float* bp = b_a + l * 8;
        const float* vp = v_a + l * 8;
#pragma unroll
        for (int j = 0; j < 8; ++j) { q8[j] = qp[j] + bp[j]; va8[j] = vp[j]; }
    }
    for (int tt = w; tt < T; tt += 8) {
        const float* pp = proj_e + (b * T + tt) * H2 + l * 8;
        float s = 0.f;
#pragma unroll
        for (int j = 0; j < 8; ++j) s += ftanh(pp[j] + q8[j]) * va8[j];
#pragma unroll
        for (int off = 32; off >= 1; off >>= 1) s += __shfl_xor(s, off);
        if (l == 0) es[tt] = s;
    }
    __syncthreads();

    // phase 3: softmax over T=128
    if (tid < 128) sred[tid] = es[tid];
    __syncthreads();
    for (int off = 64; off >= 1; off >>= 1) {
        if (tid < off) sred[tid] = fmaxf(sred[tid], sred[tid + off]);
        __syncthreads();
    }
    float M = sred[0];
    __syncthreads();
    float ev = 0.f;
    if (tid < 128) { ev = __expf(es[tid] - M); sred[tid] = ev; }
    __syncthreads();
    for (int off = 64; off >= 1; off >>= 1) {
        if (tid < off) sred[tid] += sred[tid + off];
        __syncthreads();
    }
    float S = sred[0];
    if (tid < 128) wsm[tid] = ev / S;
    __syncthreads();

    // phase 4: ctx -> xcat[256:768]
    {
        int kk = tid;
        float acc = 0.f;
        const float* eo = enc_out + b * T * H2 + kk;
        for (int tt = 0; tt < T; ++tt) acc = fmaf(wsm[tt], eo[tt * H2], acc);
        xcat[b * 768 + 256 + kk] = acc;
    }
}

// ---------------- K2: decoder LSTMCell. grid 256 (2 units each) x 256
__global__ __launch_bounds__(256) void k_declstm(
    const float* __restrict__ xcat, const float* __restrict__ h_cur,
    float* __restrict__ h_nxt, float* __restrict__ c_dec, float* __restrict__ h2T,
    const float* __restrict__ Wih, const float* __restrict__ Whh,
    const float* __restrict__ bih, const float* __restrict__ bhh) {
    int tid = threadIdx.x;
    int u0 = blockIdx.x * 2;
    int b = tid & 31, q = tid >> 5;
    int g = q & 3, ul = q >> 2;
    int u = u0 + ul;
    int grow = g * H2 + u;
    float a0 = 0, a1 = 0, a2 = 0, a3 = 0;
    const float* xr = xcat + b * 768;
    const float* wr = Wih + grow * 768;
    for (int k = 0; k < 768; k += 4) {
        float4 w = *(const float4*)(wr + k);
        float4 xv = *(const float4*)(xr + k);
        a0 = fmaf(w.x, xv.x, a0); a1 = fmaf(w.y, xv.y, a1);
        a2 = fmaf(w.z, xv.z, a2); a3 = fmaf(w.w, xv.w, a3);
    }
    const float* hr = h_cur + b * H2;
    const float* wr2 = Whh + grow * H2;
    for (int k = 0; k < H2; k += 4) {
        float4 w = *(const float4*)(wr2 + k);
        float4 xv = *(const float4*)(hr + k);
        a0 = fmaf(w.x, xv.x, a0); a1 = fmaf(w.y, xv.y, a1);
        a2 = fmaf(w.z, xv.z, a2); a3 = fmaf(w.w, xv.w, a3);
    }
    float z = (a0 + a1) + (a2 + a3) + bih[grow] + bhh[grow];
    __shared__ float zs[8][32];
    zs[q][b] = z;
    __syncthreads();
    if (tid < 64) {
        int b2 = tid & 31, ul2 = tid >> 5;
        int uu = u0 + ul2;
        float zi = zs[ul2 * 4 + 0][b2], zf = zs[ul2 * 4 + 1][b2];
        float zg = zs[ul2 * 4 + 2][b2], zo = zs[ul2 * 4 + 3][b2];
        float cp = c_dec[b2 * H2 + uu];
        float c2 = sigf(zf) * cp + sigf(zi) * ftanh(zg);
        float h2 = sigf(zo) * ftanh(c2);
        c_dec[b2 * H2 + uu] = c2;
        h_nxt[b2 * H2 + uu] = h2;
        h2T[uu * B + b2] = h2;
    }
}

// ---------------- K3: logits (+ q piggyback rows). grid 254 = rblk(127) x bt(2)
// rblk<125: Wout rows -> raw logits to d_out + per-wave (max,argmax,sumexp) partials
// rblk>=125: Wa_h rows -> q_buf for NEXT step
__global__ __launch_bounds__(256) void k_logits(
    const float* __restrict__ Wout, const float* __restrict__ Wa_h,
    const float* __restrict__ bout, const float* __restrict__ h2T,
    float* __restrict__ out, float* __restrict__ q_buf,
    float* __restrict__ Pm, float* __restrict__ Ps, int* __restrict__ Pi, int t) {
    int tid = threadIdx.x;
    int bt = blockIdx.x & 1;
    int rblk = blockIdx.x >> 1;
    int row = rblk * 256 + tid;
    int b0 = bt * 16;
    const float* Wrow = (rblk < 125) ? (Wout + (size_t)row * H2)
                                     : (Wa_h + (size_t)(row - V) * H2);
    const float* Xp = h2T + b0;   // h2T[k*B + b], wave-uniform address
    float acc[16];
#pragma unroll
    for (int i = 0; i < 16; ++i) acc[i] = 0.f;
    for (int k = 0; k < H2; k += 4) {
        float4 w = *(const float4*)(Wrow + k);
#pragma unroll
        for (int kk = 0; kk < 4; ++kk) {
            const float* xr = Xp + (k + kk) * B;
            float wk = (kk == 0) ? w.x : (kk == 1) ? w.y : (kk == 2) ? w.z : w.w;
#pragma unroll
            for (int i = 0; i < 16; ++i) acc[i] = fmaf(wk, xr[i], acc[i]);
        }
    }
    if (rblk < 125) {
        float bo = bout[row];
        int l = tid & 63;
        int wt = rblk * 4 + (tid >> 6);
        float keep_m = 0.f, keep_s = 0.f; int keep_i = 0;
        for (int i = 0; i < 16; ++i) {
            float v = acc[i] + bo;
            out[((size_t)(b0 + i) * T + t) * V + row] = v;
            float m = v; int mi = row;
#pragma unroll
            for (int off = 1; off < 64; off <<= 1) {
                float om = __shfl_xor(m, off); int oi = __shfl_xor(mi, off);
                if (om > m || (om == m && oi < mi)) { m = om; mi = oi; }
            }
            float e = __expf(v - m);
#pragma unroll
            for (int off = 1; off < 64; off <<= 1) e += __shfl_xor(e, off);
            if (l == i) { keep_m = m; keep_i = mi; keep_s = e; }
        }
        if (l < 16) {
            Pm[wt * 32 + b0 + l] = keep_m;
            Ps[wt * 32 + b0 + l] = keep_s;
            Pi[wt * 32 + b0 + l] = keep_i;
        }
    } else {
        int jrow = row - V;
#pragma unroll
        for (int i = 0; i < 16; ++i) q_buf[(b0 + i) * H2 + jrow] = acc[i];
    }
}

// ---------------- final: out = logits - lse[b*T+t]
__global__ __launch_bounds__(256) void k_norm(float* __restrict__ out,
                                              const float* __restrict__ lse) {
    const int total4 = B * T * V / 4;   // 32,768,000
    int stride = gridDim.x * 256;
    for (int i4 = blockIdx.x * 256 + threadIdx.x; i4 < total4; i4 += stride) {
        int rowv = i4 / (V / 4);
        float l = lse[rowv];
        float4* p = (float4*)out + i4;
        float4 v = *p;
        v.x -= l; v.y -= l; v.z -= l; v.w -= l;
        *p = v;
    }
}

extern "C" void kernel_launch(void* const* d_in, const int* in_sizes, int n_in,
                              void* d_out, int out_size, void* d_ws, size_t ws_size,
                              hipStream_t stream) {
    const int* x          = (const int*)d_in[0];
    const float* emb_enc  = (const float*)d_in[1];
    const float* Wih_f    = (const float*)d_in[2];
    const float* Whh_f    = (const float*)d_in[3];
    const float* bih_f    = (const float*)d_in[4];
    const float* bhh_f    = (const float*)d_in[5];
    const float* Wih_b    = (const float*)d_in[6];
    const float* Whh_b    = (const float*)d_in[7];
    const float* bih_b    = (const float*)d_in[8];
    const float* bhh_b    = (const float*)d_in[9];
    const float* emb_dec  = (const float*)d_in[10];
    const float* Wa_h     = (const float*)d_in[11];
    const float* Wa_e     = (const float*)d_in[12];
    const float* v_a      = (const float*)d_in[13];
    const float* b_a      = (const float*)d_in[14];
    const float* Wih_d    = (const float*)d_in[15];
    const float* Whh_d    = (const float*)d_in[16];
    const float* bih_d    = (const float*)d_in[17];
    const float* bhh_d    = (const float*)d_in[18];
    const float* Wout     = (const float*)d_in[19];
    const float* bout     = (const float*)d_in[20];
    float* out = (float*)d_out;

    float* ws      = (float*)d_ws;
    float* E       = ws;                   // 1,048,576
    float* enc_out = E + 1048576;          // 2,097,152
    float* proj_e  = enc_out + 2097152;    // 2,097,152
    float* h_enc   = proj_e + 2097152;     // 2 x 16384 (ping-pong)
    float* c_enc   = h_enc + 32768;        // 16384
    float* h_dec   = c_enc + 16384;        // 2 x 16384 (ping-pong)
    float* c_dec   = h_dec + 32768;        // 16384
    float* h2T     = c_dec + 16384;        // 16384 (k-major h, fp32)
    float* xcat    = h2T + 16384;          // 24576
    float* q_buf   = xcat + 24576;         // 16384
    float* Pm      = q_buf + 16384;        // 16000 (500 wave-tiles x 32 b)
    float* Ps      = Pm + 16000;           // 16000
    float* lse     = Ps + 16000;           // 4096
    int*   Pi      = (int*)(lse + 4096);   // 16000 ints

    hipMemsetAsync(h_enc, 0, (32768 + 16384) * sizeof(float), stream);
    k_embed<<<4096, 256, 0, stream>>>(x, emb_enc, E);

    for (int t = 0; t < T; ++t) {
        const float* hc = h_enc + (t & 1) * 16384;
        float* hn = h_enc + ((t + 1) & 1) * 16384;
        k_enc_step<<<256, 256, 0, stream>>>(E, hc, hn, c_enc, enc_out,
                                            Wih_f, Whh_f, bih_f, bhh_f,
                                            Wih_b, Whh_b, bih_b, bhh_b, t);
    }
    k_proj<<<256, 256, 0, stream>>>(enc_out, Wa_e, proj_e);
    k_init_dec<<<64, 256, 0, stream>>>(h_enc, c_enc, h_dec, c_dec, h2T);
    k_qinit<<<64, 256, 0, stream>>>(h_dec, Wa_h, q_buf);

    for (int t = 0; t < T; ++t) {
        k_attn<<<32, 512, 0, stream>>>(proj_e, enc_out, emb_dec, q_buf, b_a, v_a,
                                       Pm, Ps, Pi, lse, xcat, t, 0);
        const float* hc = h_dec + (t & 1) * 16384;
        float* hn = h_dec + ((t + 1) & 1) * 16384;
        k_declstm<<<256, 256, 0, stream>>>(xcat, hc, hn, c_dec, h2T,
                                           Wih_d, Whh_d, bih_d, bhh_d);
        k_logits<<<254, 256, 0, stream>>>(Wout, Wa_h, bout, h2T, out, q_buf,
                                          Pm, Ps, Pi, t);
    }
    k_attn<<<32, 512, 0, stream>>>(proj_e, enc_out, emb_dec, q_buf, b_a, v_a,
                                   Pm, Ps, Pi, lse, xcat, T, 1);
    k_norm<<<4096, 256, 0, stream>>>(out, lse);
}